// Round 10
// baseline (253.637 us; speedup 1.0000x reference)
//
#include <hip/hip_runtime.h>
#include <hip/hip_fp16.h>

#define BB   4
#define FF   128
#define CC   8
#define LSEQ 196608        // 256*256*3
#define GRID 768           // blocks = chunks; 3 blocks/CU x 256 CU = co-resident
#define CL   256           // LSEQ / GRID
#define TL   16            // positions per MFMA tile
#define NT   16            // CL / TL
#define TS   12            // tbuf row stride (floats): 8 y + 1 q + 3 pad
#define CPL  12            // chunks per lane in phase 2 (GRID / 64)

typedef _Float16 half8 __attribute__((ext_vector_type(8)));
typedef float    f32x4 __attribute__((ext_vector_type(4)));

__global__ __launch_bounds__(64) void k_zero(int* ctr) {
    if (threadIdx.x < 2) ctr[threadIdx.x] = 0;
}

static __device__ __forceinline__ void gridbar(int* ctr) {
    __syncthreads();                 // implicit vmcnt(0): payload atomics done
    if (threadIdx.x == 0) {
        __threadfence();             // release
        atomicAdd(ctr, 1);
        while (atomicAdd(ctr, 0) < GRID) __builtin_amdgcn_s_sleep(2);
        __threadfence();             // acquire
    }
    __syncthreads();
}

// ---- ONE fused kernel: chunk sums -> grid scan -> scan+MFMA+store ----
// 768 blocks x 256 thr, wave = batch, block = 256-position chunk.
__global__ __launch_bounds__(256, 3) void k_fused(
    const int* __restrict__ ex, const float* __restrict__ W_in,
    const float* __restrict__ b_in, const float* __restrict__ pos,
    const float* __restrict__ Wf, const float* __restrict__ bfin,
    int* __restrict__ ctr, float* __restrict__ csum, float* __restrict__ out)
{
    __shared__ __align__(16) __half stile[4][TL][FF];   // 16 KB
    __shared__ __align__(16) float  tbuf[4][TL][TS];    // 3 KB

    const int t    = threadIdx.x;
    const int wu   = __builtin_amdgcn_readfirstlane(t >> 6);   // wave = batch
    const int lane = t & 63;
    const int lo   = lane & 15;
    const int hi   = lane >> 4;
    const int ch   = blockIdx.x;
    const int l0   = ch * CL;

    const float2 w  = *(const float2*)&W_in[2 * lane];
    const float2 bb = *(const float2*)&b_in[2 * lane];
    const int* exu = ex + (size_t)wu * LSEQ + l0;   // wave-uniform -> s_loads

    // ---------------- phase 1: chunk feature sums (pos cold read) ----------
    float* cp = &csum[((size_t)wu * GRID + ch) * FF + 2 * lane];
    {
        float2 a = {0.f, 0.f};
        const float* pp = pos + (size_t)l0 * FF + 2 * lane;
        #pragma unroll 4
        for (int l = 0; l < CL; ++l) {
            float2 p = *(const float2*)pp; pp += FF;
            float x = (float)exu[l] * 0.5f - 3.0f;
            a.x += fmaxf(fmaf(x, w.x, p.x + bb.x), 0.f);
            a.y += fmaxf(fmaf(x, w.y, p.y + bb.y), 0.f);
        }
        atomicExch(cp,     a.x);     // device-scope publish (cross-XCD safe)
        atomicExch(cp + 1, a.y);
    }

    gridbar(&ctr[0]);

    // ---------------- phase 2: exclusive scan along chunks ----------------
    // 256 streams = (batch, feature-pair); blocks 0..63, wave = stream,
    // lane owns CPL consecutive chunks. All csum access via device atomics.
    if (blockIdx.x < 64) {
        const int sid = blockIdx.x * 4 + wu;        // 0..255
        const int b   = sid >> 6;                    // batch
        const int fp  = sid & 63;                    // feature pair
        float* base = csum + (size_t)b * GRID * FF + 2 * fp;
        float2 vals[CPL];
        float2 tot = {0.f, 0.f};
        #pragma unroll
        for (int i = 0; i < CPL; ++i) {
            float* p = base + (size_t)(lane * CPL + i) * FF;
            vals[i].x = atomicAdd(p,     0.f);
            vals[i].y = atomicAdd(p + 1, 0.f);
            tot.x += vals[i].x; tot.y += vals[i].y;
        }
        float vx = tot.x, vy = tot.y;                // wave inclusive scan
        #pragma unroll
        for (int d = 1; d < 64; d <<= 1) {
            float ux = __shfl_up(vx, d);
            float uy = __shfl_up(vy, d);
            if (lane >= d) { vx += ux; vy += uy; }
        }
        float2 excl = {vx - tot.x, vy - tot.y};
        #pragma unroll
        for (int i = 0; i < CPL; ++i) {
            float* p = base + (size_t)(lane * CPL + i) * FF;
            atomicExch(p,     excl.x);
            atomicExch(p + 1, excl.y);
            excl.x += vals[i].x; excl.y += vals[i].y;
        }
    }

    gridbar(&ctr[1]);

    // ---------------- phase 3: scan + MFMA + normalize + store -------------
    half8 wfrag[4];
    #pragma unroll
    for (int kk = 0; kk < 4; ++kk) {
        #pragma unroll
        for (int j = 0; j < 8; ++j) {
            int k = kk * 32 + hi * 8 + j;
            float wv = (lo < CC) ? Wf[k * CC + lo] : 0.f;
            wfrag[kk][j] = (_Float16)wv;
        }
    }
    const f32x4 bf0 = *(const f32x4*)&bfin[0];
    const f32x4 bf1 = *(const f32x4*)&bfin[4];

    float2 s;
    s.x = atomicAdd(cp,     0.f);    // own exclusive prefix (coherent read)
    s.y = atomicAdd(cp + 1, 0.f);

    char* sbase = (char*)&stile[wu][0][0];
    const int ra0 = lo * 256 + ((hi * 16) ^ ((lo & 7) << 4));
    const int wa  = 4 * lane;
    const int jq = lo - 4 * hi;
    const bool isdiag = (jq >= 0) && (jq < 4);

    for (int tile = 0; tile < NT; ++tile) {
        // ---- phase A: scan TL positions, lane = feature-pair, 1 batch ----
        const float* pp = pos + (size_t)(l0 + tile * TL) * FF + 2 * lane;
        #pragma unroll
        for (int l = 0; l < TL; ++l) {
            float2 p = *(const float2*)pp; pp += FF;
            float x = (float)exu[tile * TL + l] * 0.5f - 3.0f;
            s.x = fmaxf(fmaf(x, w.x, p.x + bb.x), 0.f) + s.x;
            s.y = fmaxf(fmaf(x, w.y, p.y + bb.y), 0.f) + s.y;
            __half2 h = __float22half2_rn(make_float2(s.x, s.y));
            *(__half2*)(sbase + l * 256 + (wa ^ ((l & 7) << 4))) = h;
        }

        // ---- phase B: MFMA matvec + self-dot ----
        f32x4 y  = {0.f, 0.f, 0.f, 0.f};
        f32x4 c2 = {0.f, 0.f, 0.f, 0.f};
        #pragma unroll
        for (int kk = 0; kk < 4; ++kk) {
            half8 a = *(half8*)(sbase + (ra0 ^ (kk << 6)));
            y  = __builtin_amdgcn_mfma_f32_16x16x32_f16(a, wfrag[kk], y, 0, 0, 0);
            c2 = __builtin_amdgcn_mfma_f32_16x16x32_f16(a, a,        c2, 0, 0, 0);
        }

        // ---- transpose raw y + diag q through tbuf (wave-private) ----
        if (lo < CC) {
            tbuf[wu][4 * hi + 0][lo] = y[0];
            tbuf[wu][4 * hi + 1][lo] = y[1];
            tbuf[wu][4 * hi + 2][lo] = y[2];
            tbuf[wu][4 * hi + 3][lo] = y[3];
        }
        if (isdiag) {
            float qd = c2[0];
            qd = (jq == 1) ? c2[1] : qd;
            qd = (jq == 2) ? c2[2] : qd;
            qd = (jq == 3) ? c2[3] : qd;
            tbuf[wu][lo][CC] = qd;
        }
        // ---- store lanes: rsqrt + bias + 2x dwordx4 ----
        if (lane < TL) {
            const float* tr = &tbuf[wu][lane][0];
            f32x4 v0 = *(const f32x4*)tr;
            f32x4 v1 = *(const f32x4*)(tr + 4);
            float rr = rsqrtf(fmaxf(tr[CC], 1e-12f));
            v0 = v0 * rr + bf0;
            v1 = v1 * rr + bf1;
            float* op = out + ((size_t)wu * LSEQ + l0 + tile * TL + lane) * CC;
            *(f32x4*)op       = v0;
            *(f32x4*)(op + 4) = v1;
        }
    }
}

extern "C" void kernel_launch(void* const* d_in, const int* in_sizes, int n_in,
                              void* d_out, int out_size, void* d_ws, size_t ws_size,
                              hipStream_t stream) {
    const int*   ex   = (const int*)d_in[0];
    const float* W_in = (const float*)d_in[1];
    const float* b_in = (const float*)d_in[2];
    const float* pos  = (const float*)d_in[3];
    const float* Wf   = (const float*)d_in[4];
    const float* bf   = (const float*)d_in[5];
    float* out  = (float*)d_out;
    int*   ctr  = (int*)d_ws;                         // 2 counters
    float* csum = (float*)((char*)d_ws + 256);        // [B][GRID][F] = 1.5 MB

    k_zero<<<1, 64, 0, stream>>>(ctr);
    k_fused<<<GRID, 256, 0, stream>>>(ex, W_in, b_in, pos, Wf, bf, ctr, csum, out);
}

// Round 11
// 236.512 us; speedup vs baseline: 1.0724x; 1.0724x over previous
//
#include <hip/hip_runtime.h>
#include <hip/hip_fp16.h>

#define BB   4
#define FF   128
#define CC   8
#define LSEQ 196608        // 256*256*3
#define GRID 768           // blocks = chunks; 3 blocks/CU x 256 CU = co-resident
#define CL   256           // LSEQ / GRID
#define TL   16            // positions per MFMA tile
#define NT   16            // CL / TL
#define TS   12            // tbuf row stride (floats): 8 y + 1 q + 3 pad
#define CPL  12            // chunks per lane in phase 2 (GRID / 64)

typedef _Float16 half8 __attribute__((ext_vector_type(8)));
typedef float    f32x4 __attribute__((ext_vector_type(4)));

__global__ __launch_bounds__(64) void k_zero(int* ctr) {
    if (threadIdx.x < 2) ctr[threadIdx.x] = 0;
}

// agent-scope coherent 64-bit load/store: plain global ops with L2-bypass
// (sc1) -> full-BW cross-XCD visibility, NO atomic-unit RMW serialization.
static __device__ __forceinline__ void cstore64(float* p, float2 v) {
    __hip_atomic_store((unsigned long long*)p,
                       __builtin_bit_cast(unsigned long long, v),
                       __ATOMIC_RELAXED, __HIP_MEMORY_SCOPE_AGENT);
}
static __device__ __forceinline__ float2 cload64(const float* p) {
    unsigned long long u =
        __hip_atomic_load((const unsigned long long*)p,
                          __ATOMIC_RELAXED, __HIP_MEMORY_SCOPE_AGENT);
    return __builtin_bit_cast(float2, u);
}

static __device__ __forceinline__ void gridbar(int* ctr) {
    __syncthreads();                 // implicit vmcnt(0): payload stores issued
    if (threadIdx.x == 0) {
        __threadfence();             // release: drain stores to L3
        atomicAdd(ctr, 1);           // single RMW per block (arrival)
        while (__hip_atomic_load(ctr, __ATOMIC_RELAXED,
                                 __HIP_MEMORY_SCOPE_AGENT) < GRID)
            __builtin_amdgcn_s_sleep(8);   // poll = plain coherent LOAD
        __threadfence();             // acquire
    }
    __syncthreads();
}

// ---- ONE fused kernel: chunk sums -> grid scan -> scan+MFMA+store ----
// 768 blocks x 256 thr, wave = batch, block = 256-position chunk.
__global__ __launch_bounds__(256, 3) void k_fused(
    const int* __restrict__ ex, const float* __restrict__ W_in,
    const float* __restrict__ b_in, const float* __restrict__ pos,
    const float* __restrict__ Wf, const float* __restrict__ bfin,
    int* __restrict__ ctr, float* __restrict__ csum, float* __restrict__ out)
{
    __shared__ __align__(16) __half stile[4][TL][FF];   // 16 KB
    __shared__ __align__(16) float  tbuf[4][TL][TS];    // 3 KB

    const int t    = threadIdx.x;
    const int wu   = __builtin_amdgcn_readfirstlane(t >> 6);   // wave = batch
    const int lane = t & 63;
    const int lo   = lane & 15;
    const int hi   = lane >> 4;
    const int ch   = blockIdx.x;
    const int l0   = ch * CL;

    const float2 w  = *(const float2*)&W_in[2 * lane];
    const float2 bb = *(const float2*)&b_in[2 * lane];
    const int* exu = ex + (size_t)wu * LSEQ + l0;   // wave-uniform -> s_loads

    // ---------------- phase 1: chunk feature sums (pos cold read) ----------
    float* cp = &csum[((size_t)wu * GRID + ch) * FF + 2 * lane];
    {
        float2 a = {0.f, 0.f};
        const float* pp = pos + (size_t)l0 * FF + 2 * lane;
        #pragma unroll 4
        for (int l = 0; l < CL; ++l) {
            float2 p = *(const float2*)pp; pp += FF;
            float x = (float)exu[l] * 0.5f - 3.0f;
            a.x += fmaxf(fmaf(x, w.x, p.x + bb.x), 0.f);
            a.y += fmaxf(fmaf(x, w.y, p.y + bb.y), 0.f);
        }
        cstore64(cp, a);             // coherent publish (cross-XCD safe)
    }

    gridbar(&ctr[0]);

    // ---------------- phase 2: exclusive scan along chunks ----------------
    // 256 streams = (batch, feature-pair); blocks 0..63, wave = stream,
    // lane owns CPL consecutive chunks. Coherent 64-bit loads/stores.
    if (blockIdx.x < 64) {
        const int sid = blockIdx.x * 4 + wu;        // 0..255
        const int b   = sid >> 6;                    // batch
        const int fp  = sid & 63;                    // feature pair
        float* base = csum + (size_t)b * GRID * FF + 2 * fp;
        float2 vals[CPL];
        float2 tot = {0.f, 0.f};
        #pragma unroll
        for (int i = 0; i < CPL; ++i) {
            vals[i] = cload64(base + (size_t)(lane * CPL + i) * FF);
            tot.x += vals[i].x; tot.y += vals[i].y;
        }
        float vx = tot.x, vy = tot.y;                // wave inclusive scan
        #pragma unroll
        for (int d = 1; d < 64; d <<= 1) {
            float ux = __shfl_up(vx, d);
            float uy = __shfl_up(vy, d);
            if (lane >= d) { vx += ux; vy += uy; }
        }
        float2 excl = {vx - tot.x, vy - tot.y};
        #pragma unroll
        for (int i = 0; i < CPL; ++i) {
            cstore64(base + (size_t)(lane * CPL + i) * FF, excl);
            excl.x += vals[i].x; excl.y += vals[i].y;
        }
    }

    gridbar(&ctr[1]);

    // ---------------- phase 3: scan + MFMA + normalize + store -------------
    half8 wfrag[4];
    #pragma unroll
    for (int kk = 0; kk < 4; ++kk) {
        #pragma unroll
        for (int j = 0; j < 8; ++j) {
            int k = kk * 32 + hi * 8 + j;
            float wv = (lo < CC) ? Wf[k * CC + lo] : 0.f;
            wfrag[kk][j] = (_Float16)wv;
        }
    }
    const f32x4 bf0 = *(const f32x4*)&bfin[0];
    const f32x4 bf1 = *(const f32x4*)&bfin[4];

    float2 s = cload64(cp);          // own exclusive prefix (coherent read)

    char* sbase = (char*)&stile[wu][0][0];
    const int ra0 = lo * 256 + ((hi * 16) ^ ((lo & 7) << 4));
    const int wa  = 4 * lane;
    const int jq = lo - 4 * hi;
    const bool isdiag = (jq >= 0) && (jq < 4);

    for (int tile = 0; tile < NT; ++tile) {
        // ---- phase A: scan TL positions, lane = feature-pair, 1 batch ----
        const float* pp = pos + (size_t)(l0 + tile * TL) * FF + 2 * lane;
        #pragma unroll
        for (int l = 0; l < TL; ++l) {
            float2 p = *(const float2*)pp; pp += FF;
            float x = (float)exu[tile * TL + l] * 0.5f - 3.0f;
            s.x = fmaxf(fmaf(x, w.x, p.x + bb.x), 0.f) + s.x;
            s.y = fmaxf(fmaf(x, w.y, p.y + bb.y), 0.f) + s.y;
            __half2 h = __float22half2_rn(make_float2(s.x, s.y));
            *(__half2*)(sbase + l * 256 + (wa ^ ((l & 7) << 4))) = h;
        }

        // ---- phase B: MFMA matvec + self-dot ----
        f32x4 y  = {0.f, 0.f, 0.f, 0.f};
        f32x4 c2 = {0.f, 0.f, 0.f, 0.f};
        #pragma unroll
        for (int kk = 0; kk < 4; ++kk) {
            half8 a = *(half8*)(sbase + (ra0 ^ (kk << 6)));
            y  = __builtin_amdgcn_mfma_f32_16x16x32_f16(a, wfrag[kk], y, 0, 0, 0);
            c2 = __builtin_amdgcn_mfma_f32_16x16x32_f16(a, a,        c2, 0, 0, 0);
        }

        // ---- transpose raw y + diag q through tbuf (wave-private) ----
        if (lo < CC) {
            tbuf[wu][4 * hi + 0][lo] = y[0];
            tbuf[wu][4 * hi + 1][lo] = y[1];
            tbuf[wu][4 * hi + 2][lo] = y[2];
            tbuf[wu][4 * hi + 3][lo] = y[3];
        }
        if (isdiag) {
            float qd = c2[0];
            qd = (jq == 1) ? c2[1] : qd;
            qd = (jq == 2) ? c2[2] : qd;
            qd = (jq == 3) ? c2[3] : qd;
            tbuf[wu][lo][CC] = qd;
        }
        // ---- store lanes: rsqrt + bias + 2x dwordx4 ----
        if (lane < TL) {
            const float* tr = &tbuf[wu][lane][0];
            f32x4 v0 = *(const f32x4*)tr;
            f32x4 v1 = *(const f32x4*)(tr + 4);
            float rr = rsqrtf(fmaxf(tr[CC], 1e-12f));
            v0 = v0 * rr + bf0;
            v1 = v1 * rr + bf1;
            float* op = out + ((size_t)wu * LSEQ + l0 + tile * TL + lane) * CC;
            *(f32x4*)op       = v0;
            *(f32x4*)(op + 4) = v1;
        }
    }
}

extern "C" void kernel_launch(void* const* d_in, const int* in_sizes, int n_in,
                              void* d_out, int out_size, void* d_ws, size_t ws_size,
                              hipStream_t stream) {
    const int*   ex   = (const int*)d_in[0];
    const float* W_in = (const float*)d_in[1];
    const float* b_in = (const float*)d_in[2];
    const float* pos  = (const float*)d_in[3];
    const float* Wf   = (const float*)d_in[4];
    const float* bf   = (const float*)d_in[5];
    float* out  = (float*)d_out;
    int*   ctr  = (int*)d_ws;                         // 2 counters
    float* csum = (float*)((char*)d_ws + 256);        // [B][GRID][F] = 1.5 MB

    k_zero<<<1, 64, 0, stream>>>(ctr);
    k_fused<<<GRID, 256, 0, stream>>>(ex, W_in, b_in, pos, Wf, bf, ctr, csum, out);
}

// Round 12
// 146.342 us; speedup vs baseline: 1.7332x; 1.6162x over previous
//
#include <hip/hip_runtime.h>
#include <hip/hip_fp16.h>

#define BB   4
#define FF   128
#define CC   8
#define LSEQ 196608        // 256*256*3
#define GRID 768           // blocks = chunks; 3 blocks/CU x 256 CU = co-resident
#define CL   256           // LSEQ / GRID
#define TL   16            // positions per MFMA tile
#define NT   16            // CL / TL
#define TS   12            // tbuf row stride (floats): 8 y + 1 q + 3 pad
#define CPL  12            // chunks per lane in phase 2 (GRID / 64)

typedef _Float16 half8 __attribute__((ext_vector_type(8)));
typedef float    f32x4 __attribute__((ext_vector_type(4)));

__global__ __launch_bounds__(64) void k_zero(int* ctr) {
    if (threadIdx.x < 2) ctr[threadIdx.x] = 0;
}

// agent-scope coherent 64-bit load/store: plain global ops with L2-bypass
// (sc1) -> full-BW cross-XCD visibility, NO atomic-unit RMW serialization.
static __device__ __forceinline__ void cstore64(float* p, float2 v) {
    __hip_atomic_store((unsigned long long*)p,
                       __builtin_bit_cast(unsigned long long, v),
                       __ATOMIC_RELAXED, __HIP_MEMORY_SCOPE_AGENT);
}
static __device__ __forceinline__ float2 cload64(const float* p) {
    unsigned long long u =
        __hip_atomic_load((const unsigned long long*)p,
                          __ATOMIC_RELAXED, __HIP_MEMORY_SCOPE_AGENT);
    return __builtin_bit_cast(float2, u);
}

// NO __threadfence: all cross-block payload uses sc1 (L2-bypass) ops, so
// there is nothing to flush from L2. __syncthreads' implicit vmcnt(0)
// guarantees payload stores completed (acked at L3) before the arrival add;
// the control dependency on the poll load orders subsequent sc1 reads.
// An agent-scope fence here would lower to buffer_wbl2/buffer_inv (bulk L2
// writeback+invalidate) -- 3072 of those were the round-10/11 disaster.
static __device__ __forceinline__ void gridbar(int* ctr) {
    __syncthreads();                 // vmcnt(0): payload stores completed
    if (threadIdx.x == 0) {
        atomicAdd(ctr, 1);           // single RMW per block (arrival)
        while (__hip_atomic_load(ctr, __ATOMIC_RELAXED,
                                 __HIP_MEMORY_SCOPE_AGENT) < GRID)
            __builtin_amdgcn_s_sleep(8);   // poll = plain coherent LOAD
    }
    __syncthreads();
}

// ---- ONE fused kernel: chunk sums -> grid scan -> scan+MFMA+store ----
// 768 blocks x 256 thr, wave = batch, block = 256-position chunk.
__global__ __launch_bounds__(256, 3) void k_fused(
    const int* __restrict__ ex, const float* __restrict__ W_in,
    const float* __restrict__ b_in, const float* __restrict__ pos,
    const float* __restrict__ Wf, const float* __restrict__ bfin,
    int* __restrict__ ctr, float* __restrict__ csum, float* __restrict__ out)
{
    __shared__ __align__(16) __half stile[4][TL][FF];   // 16 KB
    __shared__ __align__(16) float  tbuf[4][TL][TS];    // 3 KB

    const int t    = threadIdx.x;
    const int wu   = __builtin_amdgcn_readfirstlane(t >> 6);   // wave = batch
    const int lane = t & 63;
    const int lo   = lane & 15;
    const int hi   = lane >> 4;
    const int ch   = blockIdx.x;
    const int l0   = ch * CL;

    const float2 w  = *(const float2*)&W_in[2 * lane];
    const float2 bb = *(const float2*)&b_in[2 * lane];
    const int* exu = ex + (size_t)wu * LSEQ + l0;   // wave-uniform -> s_loads

    // ---------------- phase 1: chunk feature sums (pos cold read) ----------
    float* cp = &csum[((size_t)wu * GRID + ch) * FF + 2 * lane];
    {
        float2 a = {0.f, 0.f};
        const float* pp = pos + (size_t)l0 * FF + 2 * lane;
        #pragma unroll 4
        for (int l = 0; l < CL; ++l) {
            float2 p = *(const float2*)pp; pp += FF;
            float x = (float)exu[l] * 0.5f - 3.0f;
            a.x += fmaxf(fmaf(x, w.x, p.x + bb.x), 0.f);
            a.y += fmaxf(fmaf(x, w.y, p.y + bb.y), 0.f);
        }
        cstore64(cp, a);             // coherent publish (cross-XCD safe)
    }

    gridbar(&ctr[0]);

    // ---------------- phase 2: exclusive scan along chunks ----------------
    // 256 streams = (batch, feature-pair); blocks 0..63, wave = stream,
    // lane owns CPL consecutive chunks. Coherent 64-bit loads/stores.
    if (blockIdx.x < 64) {
        const int sid = blockIdx.x * 4 + wu;        // 0..255
        const int b   = sid >> 6;                    // batch
        const int fp  = sid & 63;                    // feature pair
        float* base = csum + (size_t)b * GRID * FF + 2 * fp;
        float2 vals[CPL];
        float2 tot = {0.f, 0.f};
        #pragma unroll
        for (int i = 0; i < CPL; ++i) {
            vals[i] = cload64(base + (size_t)(lane * CPL + i) * FF);
            tot.x += vals[i].x; tot.y += vals[i].y;
        }
        float vx = tot.x, vy = tot.y;                // wave inclusive scan
        #pragma unroll
        for (int d = 1; d < 64; d <<= 1) {
            float ux = __shfl_up(vx, d);
            float uy = __shfl_up(vy, d);
            if (lane >= d) { vx += ux; vy += uy; }
        }
        float2 excl = {vx - tot.x, vy - tot.y};
        #pragma unroll
        for (int i = 0; i < CPL; ++i) {
            cstore64(base + (size_t)(lane * CPL + i) * FF, excl);
            excl.x += vals[i].x; excl.y += vals[i].y;
        }
    }

    gridbar(&ctr[1]);

    // ---------------- phase 3: scan + MFMA + normalize + store -------------
    half8 wfrag[4];
    #pragma unroll
    for (int kk = 0; kk < 4; ++kk) {
        #pragma unroll
        for (int j = 0; j < 8; ++j) {
            int k = kk * 32 + hi * 8 + j;
            float wv = (lo < CC) ? Wf[k * CC + lo] : 0.f;
            wfrag[kk][j] = (_Float16)wv;
        }
    }
    const f32x4 bf0 = *(const f32x4*)&bfin[0];
    const f32x4 bf1 = *(const f32x4*)&bfin[4];

    float2 s = cload64(cp);          // own exclusive prefix (coherent read)

    char* sbase = (char*)&stile[wu][0][0];
    const int ra0 = lo * 256 + ((hi * 16) ^ ((lo & 7) << 4));
    const int wa  = 4 * lane;
    const int jq = lo - 4 * hi;
    const bool isdiag = (jq >= 0) && (jq < 4);

    for (int tile = 0; tile < NT; ++tile) {
        // ---- phase A: scan TL positions, lane = feature-pair, 1 batch ----
        const float* pp = pos + (size_t)(l0 + tile * TL) * FF + 2 * lane;
        #pragma unroll
        for (int l = 0; l < TL; ++l) {
            float2 p = *(const float2*)pp; pp += FF;
            float x = (float)exu[tile * TL + l] * 0.5f - 3.0f;
            s.x = fmaxf(fmaf(x, w.x, p.x + bb.x), 0.f) + s.x;
            s.y = fmaxf(fmaf(x, w.y, p.y + bb.y), 0.f) + s.y;
            __half2 h = __float22half2_rn(make_float2(s.x, s.y));
            *(__half2*)(sbase + l * 256 + (wa ^ ((l & 7) << 4))) = h;
        }

        // ---- phase B: MFMA matvec + self-dot ----
        f32x4 y  = {0.f, 0.f, 0.f, 0.f};
        f32x4 c2 = {0.f, 0.f, 0.f, 0.f};
        #pragma unroll
        for (int kk = 0; kk < 4; ++kk) {
            half8 a = *(half8*)(sbase + (ra0 ^ (kk << 6)));
            y  = __builtin_amdgcn_mfma_f32_16x16x32_f16(a, wfrag[kk], y, 0, 0, 0);
            c2 = __builtin_amdgcn_mfma_f32_16x16x32_f16(a, a,        c2, 0, 0, 0);
        }

        // ---- transpose raw y + diag q through tbuf (wave-private) ----
        if (lo < CC) {
            tbuf[wu][4 * hi + 0][lo] = y[0];
            tbuf[wu][4 * hi + 1][lo] = y[1];
            tbuf[wu][4 * hi + 2][lo] = y[2];
            tbuf[wu][4 * hi + 3][lo] = y[3];
        }
        if (isdiag) {
            float qd = c2[0];
            qd = (jq == 1) ? c2[1] : qd;
            qd = (jq == 2) ? c2[2] : qd;
            qd = (jq == 3) ? c2[3] : qd;
            tbuf[wu][lo][CC] = qd;
        }
        // ---- store lanes: rsqrt + bias + 2x dwordx4 ----
        if (lane < TL) {
            const float* tr = &tbuf[wu][lane][0];
            f32x4 v0 = *(const f32x4*)tr;
            f32x4 v1 = *(const f32x4*)(tr + 4);
            float rr = rsqrtf(fmaxf(tr[CC], 1e-12f));
            v0 = v0 * rr + bf0;
            v1 = v1 * rr + bf1;
            float* op = out + ((size_t)wu * LSEQ + l0 + tile * TL + lane) * CC;
            *(f32x4*)op       = v0;
            *(f32x4*)(op + 4) = v1;
        }
    }
}

extern "C" void kernel_launch(void* const* d_in, const int* in_sizes, int n_in,
                              void* d_out, int out_size, void* d_ws, size_t ws_size,
                              hipStream_t stream) {
    const int*   ex   = (const int*)d_in[0];
    const float* W_in = (const float*)d_in[1];
    const float* b_in = (const float*)d_in[2];
    const float* pos  = (const float*)d_in[3];
    const float* Wf   = (const float*)d_in[4];
    const float* bf   = (const float*)d_in[5];
    float* out  = (float*)d_out;
    int*   ctr  = (int*)d_ws;                         // 2 counters
    float* csum = (float*)((char*)d_ws + 256);        // [B][GRID][F] = 1.5 MB

    k_zero<<<1, 64, 0, stream>>>(ctr);
    k_fused<<<GRID, 256, 0, stream>>>(ex, W_in, b_in, pos, Wf, bf, ctr, csum, out);
}

// Round 13
// 86.081 us; speedup vs baseline: 2.9465x; 1.7001x over previous
//
#include <hip/hip_runtime.h>
#include <hip/hip_fp16.h>

#define BB   4
#define FF   128
#define CC   8
#define LSEQ 196608        // 256*256*3
#define GRID 1536          // chunks
#define CL   128           // LSEQ / GRID
#define TL   16            // positions per MFMA tile
#define NT   8             // CL / TL
#define TS   12            // tbuf row stride (floats): 8 y + 1 q + 3 pad
#define CPL  24            // chunks per lane in phase 2 (GRID / 64)

typedef _Float16 half8 __attribute__((ext_vector_type(8)));
typedef float    f32x4 __attribute__((ext_vector_type(4)));

// ---------------- P1: per-chunk feature sums (pos cold read) ----------------
// 1536 blocks x 256 thr; wave = batch, lane = feature-pair.
__global__ __launch_bounds__(256) void k_p1(
    const int* __restrict__ ex, const float* __restrict__ W_in,
    const float* __restrict__ b_in, const float* __restrict__ pos,
    float* __restrict__ csum)
{
    const int t    = threadIdx.x;
    const int wu   = __builtin_amdgcn_readfirstlane(t >> 6);
    const int lane = t & 63;
    const int ch   = blockIdx.x;
    const int l0   = ch * CL;

    const float2 w  = *(const float2*)&W_in[2 * lane];
    const float2 bb = *(const float2*)&b_in[2 * lane];
    const int* exu = ex + (size_t)wu * LSEQ + l0;   // wave-uniform -> s_loads

    float2 a = {0.f, 0.f};
    const float* pp = pos + (size_t)l0 * FF + 2 * lane;
    #pragma unroll 4
    for (int l = 0; l < CL; ++l) {
        float2 p = *(const float2*)pp; pp += FF;
        float x = (float)exu[l] * 0.5f - 3.0f;
        a.x += fmaxf(fmaf(x, w.x, p.x + bb.x), 0.f);
        a.y += fmaxf(fmaf(x, w.y, p.y + bb.y), 0.f);
    }
    *(float2*)&csum[((size_t)wu * GRID + ch) * FF + 2 * lane] = a;
}

// ---------------- P2: exclusive scan along chunks ----------------
// 64 blocks x 256 thr; wave = stream (batch, feature-pair); lane owns CPL chunks.
__global__ __launch_bounds__(256) void k_p2(float* __restrict__ csum)
{
    const int t    = threadIdx.x;
    const int wu   = __builtin_amdgcn_readfirstlane(t >> 6);
    const int lane = t & 63;
    const int sid  = blockIdx.x * 4 + wu;        // 0..255
    const int b    = sid >> 6;                   // batch
    const int fp   = sid & 63;                   // feature pair
    float* base = csum + (size_t)b * GRID * FF + 2 * fp;

    float2 vals[CPL];
    float2 tot = {0.f, 0.f};
    #pragma unroll
    for (int i = 0; i < CPL; ++i) {
        vals[i] = *(const float2*)(base + (size_t)(lane * CPL + i) * FF);
        tot.x += vals[i].x; tot.y += vals[i].y;
    }
    float vx = tot.x, vy = tot.y;                // wave inclusive scan
    #pragma unroll
    for (int d = 1; d < 64; d <<= 1) {
        float ux = __shfl_up(vx, d);
        float uy = __shfl_up(vy, d);
        if (lane >= d) { vx += ux; vy += uy; }
    }
    float2 excl = {vx - tot.x, vy - tot.y};
    #pragma unroll
    for (int i = 0; i < CPL; ++i) {
        *(float2*)(base + (size_t)(lane * CPL + i) * FF) = excl;
        excl.x += vals[i].x; excl.y += vals[i].y;
    }
}

// ---------------- P3: scan + MFMA + normalize + store ----------------
// 1536 blocks x 256 thr; wave = batch; validated R12 machinery.
__global__ __launch_bounds__(256) void k_p3(
    const int* __restrict__ ex, const float* __restrict__ W_in,
    const float* __restrict__ b_in, const float* __restrict__ pos,
    const float* __restrict__ Wf, const float* __restrict__ bfin,
    const float* __restrict__ csum, float* __restrict__ out)
{
    __shared__ __align__(16) __half stile[4][TL][FF];   // 16 KB
    __shared__ __align__(16) float  tbuf[4][TL][TS];    // 3 KB

    const int t    = threadIdx.x;
    const int wu   = __builtin_amdgcn_readfirstlane(t >> 6);   // wave = batch
    const int lane = t & 63;
    const int lo   = lane & 15;
    const int hi   = lane >> 4;
    const int ch   = blockIdx.x;
    const int l0   = ch * CL;

    const float2 w  = *(const float2*)&W_in[2 * lane];
    const float2 bb = *(const float2*)&b_in[2 * lane];
    const int* exu = ex + (size_t)wu * LSEQ + l0;

    half8 wfrag[4];
    #pragma unroll
    for (int kk = 0; kk < 4; ++kk) {
        #pragma unroll
        for (int j = 0; j < 8; ++j) {
            int k = kk * 32 + hi * 8 + j;
            float wv = (lo < CC) ? Wf[k * CC + lo] : 0.f;
            wfrag[kk][j] = (_Float16)wv;
        }
    }
    const f32x4 bf0 = *(const f32x4*)&bfin[0];
    const f32x4 bf1 = *(const f32x4*)&bfin[4];

    float2 s = *(const float2*)&csum[((size_t)wu * GRID + ch) * FF + 2 * lane];

    char* sbase = (char*)&stile[wu][0][0];
    const int ra0 = lo * 256 + ((hi * 16) ^ ((lo & 7) << 4));
    const int wa  = 4 * lane;
    const int jq = lo - 4 * hi;
    const bool isdiag = (jq >= 0) && (jq < 4);

    for (int tile = 0; tile < NT; ++tile) {
        // ---- phase A: scan TL positions, lane = feature-pair, 1 batch ----
        const float* pp = pos + (size_t)(l0 + tile * TL) * FF + 2 * lane;
        #pragma unroll
        for (int l = 0; l < TL; ++l) {
            float2 p = *(const float2*)pp; pp += FF;
            float x = (float)exu[tile * TL + l] * 0.5f - 3.0f;
            s.x = fmaxf(fmaf(x, w.x, p.x + bb.x), 0.f) + s.x;
            s.y = fmaxf(fmaf(x, w.y, p.y + bb.y), 0.f) + s.y;
            __half2 h = __float22half2_rn(make_float2(s.x, s.y));
            *(__half2*)(sbase + l * 256 + (wa ^ ((l & 7) << 4))) = h;
        }

        // ---- phase B: MFMA matvec + self-dot ----
        f32x4 y  = {0.f, 0.f, 0.f, 0.f};
        f32x4 c2 = {0.f, 0.f, 0.f, 0.f};
        #pragma unroll
        for (int kk = 0; kk < 4; ++kk) {
            half8 a = *(half8*)(sbase + (ra0 ^ (kk << 6)));
            y  = __builtin_amdgcn_mfma_f32_16x16x32_f16(a, wfrag[kk], y, 0, 0, 0);
            c2 = __builtin_amdgcn_mfma_f32_16x16x32_f16(a, a,        c2, 0, 0, 0);
        }

        // ---- transpose raw y + diag q through tbuf (wave-private) ----
        if (lo < CC) {
            tbuf[wu][4 * hi + 0][lo] = y[0];
            tbuf[wu][4 * hi + 1][lo] = y[1];
            tbuf[wu][4 * hi + 2][lo] = y[2];
            tbuf[wu][4 * hi + 3][lo] = y[3];
        }
        if (isdiag) {
            float qd = c2[0];
            qd = (jq == 1) ? c2[1] : qd;
            qd = (jq == 2) ? c2[2] : qd;
            qd = (jq == 3) ? c2[3] : qd;
            tbuf[wu][lo][CC] = qd;
        }
        // ---- store lanes: rsqrt + bias + 2x dwordx4 ----
        if (lane < TL) {
            const float* tr = &tbuf[wu][lane][0];
            f32x4 v0 = *(const f32x4*)tr;
            f32x4 v1 = *(const f32x4*)(tr + 4);
            float rr = rsqrtf(fmaxf(tr[CC], 1e-12f));
            v0 = v0 * rr + bf0;
            v1 = v1 * rr + bf1;
            float* op = out + ((size_t)wu * LSEQ + l0 + tile * TL + lane) * CC;
            *(f32x4*)op       = v0;
            *(f32x4*)(op + 4) = v1;
        }
    }
}

extern "C" void kernel_launch(void* const* d_in, const int* in_sizes, int n_in,
                              void* d_out, int out_size, void* d_ws, size_t ws_size,
                              hipStream_t stream) {
    const int*   ex   = (const int*)d_in[0];
    const float* W_in = (const float*)d_in[1];
    const float* b_in = (const float*)d_in[2];
    const float* pos  = (const float*)d_in[3];
    const float* Wf   = (const float*)d_in[4];
    const float* bf   = (const float*)d_in[5];
    float* out  = (float*)d_out;
    float* csum = (float*)d_ws;                       // [B][GRID][F] = 3 MB

    k_p1<<<GRID, 256, 0, stream>>>(ex, W_in, b_in, pos, csum);
    k_p2<<<64,   256, 0, stream>>>(csum);
    k_p3<<<GRID, 256, 0, stream>>>(ex, W_in, b_in, pos, Wf, bf, csum, out);
}